// Round 8
// baseline (171.760 us; speedup 1.0000x reference)
//
#include <hip/hip_runtime.h>

typedef __fp16   fp16x2  __attribute__((ext_vector_type(2)));
typedef _Float16 half4   __attribute__((ext_vector_type(4)));
typedef float    floatx4 __attribute__((ext_vector_type(4)));

// Final act (once per c-step): t = 1 - 2/(2^a+1), hardware exp2 + rcp.
__device__ __forceinline__ float act_pre(float a) {
    float r = __builtin_amdgcn_rcpf(__builtin_amdgcn_exp2f(a) + 1.0f);
    return fmaf(-2.0f, r, 1.0f);
}

// Four r-acts r_i = 1/(2^{a_i}+1) with ONE hardware rcp via Montgomery
// batch inversion (named scalars, prefix depth 3).
// Safety: d_i >= 1 always (no underflow; rcp args >= 1). NaN would need some
// d_i = inf, i.e. a_i >= 128 -- hard bounds are ~100 (layer 0) / ~29 (hidden).
// If the PRODUCT overflows to inf, walk-back returns r=0 vs true r <= 2^-40:
// graceful and invisible at f16 resolution.
__device__ __forceinline__ floatx4 ract4(floatx4 a) {
    float d0 = __builtin_amdgcn_exp2f(a[0]) + 1.0f;
    float d1 = __builtin_amdgcn_exp2f(a[1]) + 1.0f;
    float d2 = __builtin_amdgcn_exp2f(a[2]) + 1.0f;
    float d3 = __builtin_amdgcn_exp2f(a[3]) + 1.0f;
    float p1 = d0 * d1;
    float p2 = p1 * d2;
    float p3 = p2 * d3;
    float q3 = __builtin_amdgcn_rcpf(p3);   // 1/(d0 d1 d2 d3)
    float r3 = q3 * p2;                     // 1/d3
    float q2 = q3 * d3;                     // 1/(d0 d1 d2)... -> 1/p2
    float r2 = q2 * p1;                     // 1/d2
    float q1 = q2 * d2;                     // 1/p1
    float r1 = q1 * d0;                     // 1/d1
    float r0 = q1 * d1;                     // 1/d0
    floatx4 r = {r0, r1, r2, r3};
    return r;
}

__device__ __forceinline__ half4 mk4f(floatx4 v) {
    fp16x2 lo = __builtin_amdgcn_cvt_pkrtz(v[0], v[1]);
    fp16x2 hi = __builtin_amdgcn_cvt_pkrtz(v[2], v[3]);
    union { fp16x2 h2[2]; half4 h4; } u;
    u.h2[0] = lo; u.h2[1] = hi;
    return u.h4;
}

__global__ __launch_bounds__(256, 4) void automaton_kernel(
    const float* __restrict__ x, const float* __restrict__ Ws,
    const float* __restrict__ bs, const float* __restrict__ Wf,
    const float* __restrict__ bf, const float* __restrict__ extra,
    float* __restrict__ out, int n_groups)
{
    const float K = 2.885390081777927f;  // 2*log2(e)
    const int tid   = blockIdx.x * blockDim.x + threadIdx.x;
    const int wave  = tid >> 6;
    const int lane  = threadIdx.x & 63;
    const int col   = lane & 15;
    const int sub   = lane >> 4;
    const int obase = sub * 4;

    const floatx4 zeroC = {0.f, 0.f, 0.f, 0.f};
    const half4   ones  = {(_Float16)1.f, (_Float16)1.f, (_Float16)1.f, (_Float16)1.f};

    float ex[12];
#pragma unroll
    for (int j = 0; j < 12; ++j) ex[j] = extra[j];

    // ---- Layer 0: live cols (scaled by K), fold extra+bias into c1 ----
    float W0c[4][4], c1[4];
#pragma unroll
    for (int e = 0; e < 4; ++e) {
        const float* row = Ws + (obase + e) * 16;
        floatx4 r0 = *(const floatx4*)(row);
        floatx4 r1 = *(const floatx4*)(row + 4);
        floatx4 r2 = *(const floatx4*)(row + 8);
        floatx4 r3 = *(const floatx4*)(row + 12);
#pragma unroll
        for (int j = 0; j < 4; ++j) W0c[e][j] = r0[j] * K;
        float c = bs[obase + e];
#pragma unroll
        for (int j = 0; j < 4; ++j) c = fmaf(r1[j], ex[j], c);
#pragma unroll
        for (int j = 0; j < 4; ++j) c = fmaf(r2[j], ex[4 + j], c);
#pragma unroll
        for (int j = 0; j < 4; ++j) c = fmaf(r3[j], ex[8 + j], c);
        c1[e] = c * K;
    }

    // ---- Hidden layers 1..3: A'' = f16(-2K*W); c'' = K*b - 0.5*(A''.1) ----
    half4 aW0, aW1, aW2, aWf;
    floatx4 bC0, bC1, bC2;
    {
        floatx4 w1 = *(const floatx4*)(Ws + 256 + col * 16 + obase);
        floatx4 w2 = *(const floatx4*)(Ws + 512 + col * 16 + obase);
        floatx4 w3 = *(const floatx4*)(Ws + 768 + col * 16 + obase);
#pragma unroll
        for (int e = 0; e < 4; ++e) {
            aW0[e] = (_Float16)(w1[e] * (-2.0f * K));
            aW1[e] = (_Float16)(w2[e] * (-2.0f * K));
            aW2[e] = (_Float16)(w3[e] * (-2.0f * K));
        }
        // ones-MFMA computes A''.1 exactly into the C/D layout we need
        floatx4 s0 = __builtin_amdgcn_mfma_f32_16x16x16f16(aW0, ones, zeroC, 0, 0, 0);
        floatx4 s1 = __builtin_amdgcn_mfma_f32_16x16x16f16(aW1, ones, zeroC, 0, 0, 0);
        floatx4 s2 = __builtin_amdgcn_mfma_f32_16x16x16f16(aW2, ones, zeroC, 0, 0, 0);
        floatx4 b1 = *(const floatx4*)(bs + 16 + obase);
        floatx4 b2 = *(const floatx4*)(bs + 32 + obase);
        floatx4 b3 = *(const floatx4*)(bs + 48 + obase);
#pragma unroll
        for (int e = 0; e < 4; ++e) {
            bC0[e] = fmaf(-0.5f, s0[e], K * b1[e]);
            bC1[e] = fmaf(-0.5f, s1[e], K * b2[e]);
            bC2[e] = fmaf(-0.5f, s2[e], K * b3[e]);
        }
        // Reduction MFMA consumes (r1 - r2): A[o,k] = -2K*Wf[k] for every o.
        floatx4 wf = *(const floatx4*)(Wf + obase);
#pragma unroll
        for (int e = 0; e < 4; ++e) aWf[e] = (_Float16)(wf[e] * (-2.0f * K));
    }

    const int g      = wave * 16 + col;
    const bool valid = (g < n_groups);
    const int gl     = valid ? g : (n_groups - 1);
    const float* xp  = x + (size_t)gl * 104;   // 26 channels * 4 floats

    float acc = 0.0f;
#pragma unroll
    for (int c = 0; c < 26; ++c) {
        floatx4 xv = *(const floatx4*)(xp + c * 4);

        // Layer 0 for both nets (net2 = rotated channels), f32 FMA -> r-act
        floatx4 z1, z2;
#pragma unroll
        for (int e = 0; e < 4; ++e) {
            float a1 = c1[e];
            a1 = fmaf(W0c[e][0], xv[0], a1);
            a1 = fmaf(W0c[e][1], xv[1], a1);
            a1 = fmaf(W0c[e][2], xv[2], a1);
            a1 = fmaf(W0c[e][3], xv[3], a1);
            float a2 = c1[e];
            a2 = fmaf(W0c[e][0], xv[2], a2);
            a2 = fmaf(W0c[e][1], xv[3], a2);
            a2 = fmaf(W0c[e][2], xv[0], a2);
            a2 = fmaf(W0c[e][3], xv[1], a2);
            z1[e] = a1; z2[e] = a2;
        }
        half4 hb1 = mk4f(ract4(z1));
        half4 hb2 = mk4f(ract4(z2));

        // Hidden layer 1: MFMA (pre-folded) -> batched r-act -> f16 B-frag
        {
            floatx4 d1 = __builtin_amdgcn_mfma_f32_16x16x16f16(aW0, hb1, bC0, 0, 0, 0);
            floatx4 d2 = __builtin_amdgcn_mfma_f32_16x16x16f16(aW0, hb2, bC0, 0, 0, 0);
            hb1 = mk4f(ract4(d1));
            hb2 = mk4f(ract4(d2));
        }
        // Hidden layer 2
        {
            floatx4 d1 = __builtin_amdgcn_mfma_f32_16x16x16f16(aW1, hb1, bC1, 0, 0, 0);
            floatx4 d2 = __builtin_amdgcn_mfma_f32_16x16x16f16(aW1, hb2, bC1, 0, 0, 0);
            hb1 = mk4f(ract4(d1));
            hb2 = mk4f(ract4(d2));
        }

        // Hidden layer 3 + fused final 16->1: feed (r1-r2), weights -2K*Wf.
        {
            floatx4 d1 = __builtin_amdgcn_mfma_f32_16x16x16f16(aW2, hb1, bC2, 0, 0, 0);
            floatx4 d2 = __builtin_amdgcn_mfma_f32_16x16x16f16(aW2, hb2, bC2, 0, 0, 0);
            floatx4 rv1 = ract4(d1);
            floatx4 rv2 = ract4(d2);
            floatx4 s = rv1 - rv2;
            half4 sb = mk4f(s);
            floatx4 dr = __builtin_amdgcn_mfma_f32_16x16x16f16(aWf, sb, zeroC, 0, 0, 0);
            acc += act_pre(dr[0]);
        }
    }
    if (lane < 16 && valid)
        out[g] = acc * 0.041875863808787856f;  // ONE_OVER_DIFF_TOT * DIFF_Q
}

extern "C" void kernel_launch(void* const* d_in, const int* in_sizes, int n_in,
                              void* d_out, int out_size, void* d_ws, size_t ws_size,
                              hipStream_t stream) {
    const float* x  = (const float*)d_in[0];
    const float* Ws = (const float*)d_in[1];
    const float* bs = (const float*)d_in[2];
    const float* Wf = (const float*)d_in[3];
    const float* bf = (const float*)d_in[4];
    const float* ex = (const float*)d_in[5];
    float* out = (float*)d_out;

    const int n_groups = out_size;              // B*N = 262144
    const int waves    = (n_groups + 15) / 16;  // 16 groups per wave
    const int blocks   = (waves + 3) / 4;       // 4 waves per block
    automaton_kernel<<<blocks, 256, 0, stream>>>(x, Ws, bs, Wf, bf, ex, out, n_groups);
}

// Round 10
// 166.407 us; speedup vs baseline: 1.0322x; 1.0322x over previous
//
#include <hip/hip_runtime.h>

typedef __fp16   fp16x2  __attribute__((ext_vector_type(2)));
typedef _Float16 half4   __attribute__((ext_vector_type(4)));
typedef float    floatx2 __attribute__((ext_vector_type(2)));
typedef float    floatx4 __attribute__((ext_vector_type(4)));

// Final act (once per c-step): t = 1 - 2/(2^a+1), hardware exp2 + rcp.
__device__ __forceinline__ float act_pre(float a) {
    float r = __builtin_amdgcn_rcpf(__builtin_amdgcn_exp2f(a) + 1.0f);
    return fmaf(-2.0f, r, 1.0f);
}

// Paired r-act: r_i = 1/(2^{a_i}+1) for the net1/net2 pair with ONE rcp
// (Montgomery-2: q = 1/(d1 d2); r1 = q d2; r2 = q d1). Chain depth 3.
// Ranges: hidden |a|<=29 -> d<=2^29+1, product <=2^58 (no overflow);
// layer-0 |a| <~ 25 at the data's max |x| (~5.6 sigma) -> product <= 2^50.
__device__ __forceinline__ floatx2 ract2(float a1, float a2) {
    float d1 = __builtin_amdgcn_exp2f(a1) + 1.0f;
    float d2 = __builtin_amdgcn_exp2f(a2) + 1.0f;
    float q  = __builtin_amdgcn_rcpf(d1 * d2);
    floatx2 r = {q * d2, q * d1};
    return r;
}

__device__ __forceinline__ half4 mk4f(floatx4 v) {
    fp16x2 lo = __builtin_amdgcn_cvt_pkrtz(v[0], v[1]);
    fp16x2 hi = __builtin_amdgcn_cvt_pkrtz(v[2], v[3]);
    union { fp16x2 h2[2]; half4 h4; } u;
    u.h2[0] = lo; u.h2[1] = hi;
    return u.h4;
}

__global__ __launch_bounds__(256, 4) void automaton_kernel(
    const float* __restrict__ x, const float* __restrict__ Ws,
    const float* __restrict__ bs, const float* __restrict__ Wf,
    const float* __restrict__ bf, const float* __restrict__ extra,
    float* __restrict__ out, int n_groups)
{
    const float K = 2.885390081777927f;  // 2*log2(e)
    const int tid   = blockIdx.x * blockDim.x + threadIdx.x;
    const int wave  = tid >> 6;
    const int lane  = threadIdx.x & 63;
    const int col   = lane & 15;
    const int sub   = lane >> 4;
    const int obase = sub * 4;

    const floatx4 zeroC = {0.f, 0.f, 0.f, 0.f};
    const half4   ones  = {(_Float16)1.f, (_Float16)1.f, (_Float16)1.f, (_Float16)1.f};

    float ex[12];
#pragma unroll
    for (int j = 0; j < 12; ++j) ex[j] = extra[j];

    // ---- Layer 0: live cols (scaled by K), fold extra+bias into c1 ----
    float W0c[4][4], c1[4];
#pragma unroll
    for (int e = 0; e < 4; ++e) {
        const float* row = Ws + (obase + e) * 16;
        floatx4 r0 = *(const floatx4*)(row);
        floatx4 r1 = *(const floatx4*)(row + 4);
        floatx4 r2 = *(const floatx4*)(row + 8);
        floatx4 r3 = *(const floatx4*)(row + 12);
#pragma unroll
        for (int j = 0; j < 4; ++j) W0c[e][j] = r0[j] * K;
        float c = bs[obase + e];
#pragma unroll
        for (int j = 0; j < 4; ++j) c = fmaf(r1[j], ex[j], c);
#pragma unroll
        for (int j = 0; j < 4; ++j) c = fmaf(r2[j], ex[4 + j], c);
#pragma unroll
        for (int j = 0; j < 4; ++j) c = fmaf(r3[j], ex[8 + j], c);
        c1[e] = c * K;
    }

    // ---- Hidden layers 1..3: A'' = f16(-2K*W); c'' = K*b - 0.5*(A''.1) ----
    half4 aW0, aW1, aW2, aWf;
    floatx4 bC0, bC1, bC2;
    {
        floatx4 w1 = *(const floatx4*)(Ws + 256 + col * 16 + obase);
        floatx4 w2 = *(const floatx4*)(Ws + 512 + col * 16 + obase);
        floatx4 w3 = *(const floatx4*)(Ws + 768 + col * 16 + obase);
#pragma unroll
        for (int e = 0; e < 4; ++e) {
            aW0[e] = (_Float16)(w1[e] * (-2.0f * K));
            aW1[e] = (_Float16)(w2[e] * (-2.0f * K));
            aW2[e] = (_Float16)(w3[e] * (-2.0f * K));
        }
        // ones-MFMA computes A''.1 exactly into the C/D layout we need
        floatx4 s0 = __builtin_amdgcn_mfma_f32_16x16x16f16(aW0, ones, zeroC, 0, 0, 0);
        floatx4 s1 = __builtin_amdgcn_mfma_f32_16x16x16f16(aW1, ones, zeroC, 0, 0, 0);
        floatx4 s2 = __builtin_amdgcn_mfma_f32_16x16x16f16(aW2, ones, zeroC, 0, 0, 0);
        floatx4 b1 = *(const floatx4*)(bs + 16 + obase);
        floatx4 b2 = *(const floatx4*)(bs + 32 + obase);
        floatx4 b3 = *(const floatx4*)(bs + 48 + obase);
#pragma unroll
        for (int e = 0; e < 4; ++e) {
            bC0[e] = fmaf(-0.5f, s0[e], K * b1[e]);
            bC1[e] = fmaf(-0.5f, s1[e], K * b2[e]);
            bC2[e] = fmaf(-0.5f, s2[e], K * b3[e]);
        }
        // Reduction MFMA consumes (r1 - r2): A[o,k] = -2K*Wf[k] for every o.
        floatx4 wf = *(const floatx4*)(Wf + obase);
#pragma unroll
        for (int e = 0; e < 4; ++e) aWf[e] = (_Float16)(wf[e] * (-2.0f * K));
    }

    const int g      = wave * 16 + col;
    const bool valid = (g < n_groups);
    const int gl     = valid ? g : (n_groups - 1);
    const float* xp  = x + (size_t)gl * 104;   // 26 channels * 4 floats

    float acc = 0.0f;
    floatx4 xv = *(const floatx4*)(xp);
#pragma unroll 2
    for (int c = 0; c < 26; ++c) {
        floatx4 xn = (c < 25) ? *(const floatx4*)(xp + (c + 1) * 4) : xv;

        // Layer 0 for both nets (net2 = rotated channels), f32 FMA -> paired r-act
        floatx4 rv1, rv2;
        {
            floatx4 z1, z2;
#pragma unroll
            for (int e = 0; e < 4; ++e) {
                float a1 = c1[e];
                a1 = fmaf(W0c[e][0], xv[0], a1);
                a1 = fmaf(W0c[e][1], xv[1], a1);
                a1 = fmaf(W0c[e][2], xv[2], a1);
                a1 = fmaf(W0c[e][3], xv[3], a1);
                float a2 = c1[e];
                a2 = fmaf(W0c[e][0], xv[2], a2);
                a2 = fmaf(W0c[e][1], xv[3], a2);
                a2 = fmaf(W0c[e][2], xv[0], a2);
                a2 = fmaf(W0c[e][3], xv[1], a2);
                z1[e] = a1; z2[e] = a2;
            }
#pragma unroll
            for (int e = 0; e < 4; ++e) {
                floatx2 rr = ract2(z1[e], z2[e]);
                rv1[e] = rr[0]; rv2[e] = rr[1];
            }
        }
        half4 hb1 = mk4f(rv1);
        half4 hb2 = mk4f(rv2);

        // Hidden layer 1: MFMA (pre-folded) -> paired r-act -> f16 B-frag
        {
            floatx4 d1 = __builtin_amdgcn_mfma_f32_16x16x16f16(aW0, hb1, bC0, 0, 0, 0);
            floatx4 d2 = __builtin_amdgcn_mfma_f32_16x16x16f16(aW0, hb2, bC0, 0, 0, 0);
#pragma unroll
            for (int e = 0; e < 4; ++e) {
                floatx2 rr = ract2(d1[e], d2[e]);
                rv1[e] = rr[0]; rv2[e] = rr[1];
            }
            hb1 = mk4f(rv1);
            hb2 = mk4f(rv2);
        }
        // Hidden layer 2
        {
            floatx4 d1 = __builtin_amdgcn_mfma_f32_16x16x16f16(aW1, hb1, bC1, 0, 0, 0);
            floatx4 d2 = __builtin_amdgcn_mfma_f32_16x16x16f16(aW1, hb2, bC1, 0, 0, 0);
#pragma unroll
            for (int e = 0; e < 4; ++e) {
                floatx2 rr = ract2(d1[e], d2[e]);
                rv1[e] = rr[0]; rv2[e] = rr[1];
            }
            hb1 = mk4f(rv1);
            hb2 = mk4f(rv2);
        }

        // Hidden layer 3 + fused final 16->1: feed (r1-r2), weights -2K*Wf.
        {
            floatx4 d1 = __builtin_amdgcn_mfma_f32_16x16x16f16(aW2, hb1, bC2, 0, 0, 0);
            floatx4 d2 = __builtin_amdgcn_mfma_f32_16x16x16f16(aW2, hb2, bC2, 0, 0, 0);
#pragma unroll
            for (int e = 0; e < 4; ++e) {
                floatx2 rr = ract2(d1[e], d2[e]);
                rv1[e] = rr[0]; rv2[e] = rr[1];
            }
            floatx4 s = rv1 - rv2;
            half4 sb = mk4f(s);
            floatx4 dr = __builtin_amdgcn_mfma_f32_16x16x16f16(aWf, sb, zeroC, 0, 0, 0);
            acc += act_pre(dr[0]);
        }
        xv = xn;
    }
    if (lane < 16 && valid)
        out[g] = acc * 0.041875863808787856f;  // ONE_OVER_DIFF_TOT * DIFF_Q
}

extern "C" void kernel_launch(void* const* d_in, const int* in_sizes, int n_in,
                              void* d_out, int out_size, void* d_ws, size_t ws_size,
                              hipStream_t stream) {
    const float* x  = (const float*)d_in[0];
    const float* Ws = (const float*)d_in[1];
    const float* bs = (const float*)d_in[2];
    const float* Wf = (const float*)d_in[3];
    const float* bf = (const float*)d_in[4];
    const float* ex = (const float*)d_in[5];
    float* out = (float*)d_out;

    const int n_groups = out_size;              // B*N = 262144
    const int waves    = (n_groups + 15) / 16;  // 16 groups per wave
    const int blocks   = (waves + 3) / 4;       // 4 waves per block
    automaton_kernel<<<blocks, 256, 0, stream>>>(x, Ws, bs, Wf, bf, ex, out, n_groups);
}

// Round 11
// 159.366 us; speedup vs baseline: 1.0778x; 1.0442x over previous
//
#include <hip/hip_runtime.h>

typedef __fp16   fp16x2  __attribute__((ext_vector_type(2)));
typedef _Float16 half4   __attribute__((ext_vector_type(4)));
typedef float    floatx2 __attribute__((ext_vector_type(2)));
typedef float    floatx4 __attribute__((ext_vector_type(4)));

// Final act: t = 1 - 2/(2^a+1), hardware exp2 + rcp.
__device__ __forceinline__ float act_pre(float a) {
    float r = __builtin_amdgcn_rcpf(__builtin_amdgcn_exp2f(a) + 1.0f);
    return fmaf(-2.0f, r, 1.0f);
}

// Paired r-act: r_i = 1/(2^{a_i}+1) for the net1/net2 pair with ONE rcp
// (Montgomery-2: q = 1/(d1 d2); r1 = q d2; r2 = q d1).
// Ranges: hidden |a|<=29, layer-0 |a|<~25 -> product <= 2^58, no overflow.
__device__ __forceinline__ floatx2 ract2(float a1, float a2) {
    float d1 = __builtin_amdgcn_exp2f(a1) + 1.0f;
    float d2 = __builtin_amdgcn_exp2f(a2) + 1.0f;
    float q  = __builtin_amdgcn_rcpf(d1 * d2);
    floatx2 r = {q * d2, q * d1};
    return r;
}

__device__ __forceinline__ half4 mk4f(floatx4 v) {
    fp16x2 lo = __builtin_amdgcn_cvt_pkrtz(v[0], v[1]);
    fp16x2 hi = __builtin_amdgcn_cvt_pkrtz(v[2], v[3]);
    union { fp16x2 h2[2]; half4 h4; } u;
    u.h2[0] = lo; u.h2[1] = hi;
    return u.h4;
}

__global__ __launch_bounds__(256, 4) void automaton_kernel(
    const float* __restrict__ x, const float* __restrict__ Ws,
    const float* __restrict__ bs, const float* __restrict__ Wf,
    const float* __restrict__ bf, const float* __restrict__ extra,
    float* __restrict__ out, int n_groups)
{
    const float K = 2.885390081777927f;  // 2*log2(e)
    const int tid   = blockIdx.x * blockDim.x + threadIdx.x;
    const int wave  = tid >> 6;
    const int lane  = threadIdx.x & 63;
    const int col   = lane & 15;
    const int sub   = lane >> 4;
    const int obase = sub * 4;

    const floatx4 zeroC = {0.f, 0.f, 0.f, 0.f};
    const half4   ones  = {(_Float16)1.f, (_Float16)1.f, (_Float16)1.f, (_Float16)1.f};

    float ex[12];
#pragma unroll
    for (int j = 0; j < 12; ++j) ex[j] = extra[j];

    // ---- Layer 0: live cols (scaled by K), fold extra+bias into c1 ----
    float W0c[4][4], c1[4];
#pragma unroll
    for (int e = 0; e < 4; ++e) {
        const float* row = Ws + (obase + e) * 16;
        floatx4 r0 = *(const floatx4*)(row);
        floatx4 r1 = *(const floatx4*)(row + 4);
        floatx4 r2 = *(const floatx4*)(row + 8);
        floatx4 r3 = *(const floatx4*)(row + 12);
#pragma unroll
        for (int j = 0; j < 4; ++j) W0c[e][j] = r0[j] * K;
        float c = bs[obase + e];
#pragma unroll
        for (int j = 0; j < 4; ++j) c = fmaf(r1[j], ex[j], c);
#pragma unroll
        for (int j = 0; j < 4; ++j) c = fmaf(r2[j], ex[4 + j], c);
#pragma unroll
        for (int j = 0; j < 4; ++j) c = fmaf(r3[j], ex[8 + j], c);
        c1[e] = c * K;
    }

    // ---- Hidden layers 1..3: A'' = f16(-2K*W); c'' = K*b - 0.5*(A''.1) ----
    half4 aW0, aW1, aW2, aWf;
    floatx4 bC0, bC1, bC2;
    {
        floatx4 w1 = *(const floatx4*)(Ws + 256 + col * 16 + obase);
        floatx4 w2 = *(const floatx4*)(Ws + 512 + col * 16 + obase);
        floatx4 w3 = *(const floatx4*)(Ws + 768 + col * 16 + obase);
#pragma unroll
        for (int e = 0; e < 4; ++e) {
            aW0[e] = (_Float16)(w1[e] * (-2.0f * K));
            aW1[e] = (_Float16)(w2[e] * (-2.0f * K));
            aW2[e] = (_Float16)(w3[e] * (-2.0f * K));
        }
        floatx4 s0 = __builtin_amdgcn_mfma_f32_16x16x16f16(aW0, ones, zeroC, 0, 0, 0);
        floatx4 s1 = __builtin_amdgcn_mfma_f32_16x16x16f16(aW1, ones, zeroC, 0, 0, 0);
        floatx4 s2 = __builtin_amdgcn_mfma_f32_16x16x16f16(aW2, ones, zeroC, 0, 0, 0);
        floatx4 b1 = *(const floatx4*)(bs + 16 + obase);
        floatx4 b2 = *(const floatx4*)(bs + 32 + obase);
        floatx4 b3 = *(const floatx4*)(bs + 48 + obase);
#pragma unroll
        for (int e = 0; e < 4; ++e) {
            bC0[e] = fmaf(-0.5f, s0[e], K * b1[e]);
            bC1[e] = fmaf(-0.5f, s1[e], K * b2[e]);
            bC2[e] = fmaf(-0.5f, s2[e], K * b3[e]);
        }
        floatx4 wf = *(const floatx4*)(Wf + obase);
#pragma unroll
        for (int e = 0; e < 4; ++e) aWf[e] = (_Float16)(wf[e] * (-2.0f * K));
    }

    const int g      = wave * 16 + col;
    const bool valid = (g < n_groups);
    const int gl     = valid ? g : (n_groups - 1);
    const float* xp  = x + (size_t)gl * 104;   // 26 channels * 4 floats

    float accA = 0.0f, accB = 0.0f;
#pragma unroll 1
    for (int c = 0; c < 13; ++c) {
        // Two independent channel streams: c (A) and c+13 (B).
        floatx4 xvA = *(const floatx4*)(xp + c * 4);
        floatx4 xvB = *(const floatx4*)(xp + (c + 13) * 4);

        // ---- Layer 0 (both nets, both streams), f32 FMA -> paired r-act ----
        floatx4 rA1, rA2, rB1, rB2;
        {
            floatx4 zA1, zA2, zB1, zB2;
#pragma unroll
            for (int e = 0; e < 4; ++e) {
                float a1 = c1[e];
                a1 = fmaf(W0c[e][0], xvA[0], a1);
                a1 = fmaf(W0c[e][1], xvA[1], a1);
                a1 = fmaf(W0c[e][2], xvA[2], a1);
                a1 = fmaf(W0c[e][3], xvA[3], a1);
                float a2 = c1[e];
                a2 = fmaf(W0c[e][0], xvA[2], a2);
                a2 = fmaf(W0c[e][1], xvA[3], a2);
                a2 = fmaf(W0c[e][2], xvA[0], a2);
                a2 = fmaf(W0c[e][3], xvA[1], a2);
                zA1[e] = a1; zA2[e] = a2;
                float b1v = c1[e];
                b1v = fmaf(W0c[e][0], xvB[0], b1v);
                b1v = fmaf(W0c[e][1], xvB[1], b1v);
                b1v = fmaf(W0c[e][2], xvB[2], b1v);
                b1v = fmaf(W0c[e][3], xvB[3], b1v);
                float b2v = c1[e];
                b2v = fmaf(W0c[e][0], xvB[2], b2v);
                b2v = fmaf(W0c[e][1], xvB[3], b2v);
                b2v = fmaf(W0c[e][2], xvB[0], b2v);
                b2v = fmaf(W0c[e][3], xvB[1], b2v);
                zB1[e] = b1v; zB2[e] = b2v;
            }
#pragma unroll
            for (int e = 0; e < 4; ++e) {
                floatx2 ra = ract2(zA1[e], zA2[e]);
                rA1[e] = ra[0]; rA2[e] = ra[1];
                floatx2 rb = ract2(zB1[e], zB2[e]);
                rB1[e] = rb[0]; rB2[e] = rb[1];
            }
        }
        half4 hA1 = mk4f(rA1), hA2 = mk4f(rA2);
        half4 hB1 = mk4f(rB1), hB2 = mk4f(rB2);

        // ---- Hidden layer 1 ----
        {
            floatx4 dA1 = __builtin_amdgcn_mfma_f32_16x16x16f16(aW0, hA1, bC0, 0, 0, 0);
            floatx4 dA2 = __builtin_amdgcn_mfma_f32_16x16x16f16(aW0, hA2, bC0, 0, 0, 0);
            floatx4 dB1 = __builtin_amdgcn_mfma_f32_16x16x16f16(aW0, hB1, bC0, 0, 0, 0);
            floatx4 dB2 = __builtin_amdgcn_mfma_f32_16x16x16f16(aW0, hB2, bC0, 0, 0, 0);
#pragma unroll
            for (int e = 0; e < 4; ++e) {
                floatx2 ra = ract2(dA1[e], dA2[e]);
                rA1[e] = ra[0]; rA2[e] = ra[1];
                floatx2 rb = ract2(dB1[e], dB2[e]);
                rB1[e] = rb[0]; rB2[e] = rb[1];
            }
            hA1 = mk4f(rA1); hA2 = mk4f(rA2);
            hB1 = mk4f(rB1); hB2 = mk4f(rB2);
        }
        // ---- Hidden layer 2 ----
        {
            floatx4 dA1 = __builtin_amdgcn_mfma_f32_16x16x16f16(aW1, hA1, bC1, 0, 0, 0);
            floatx4 dA2 = __builtin_amdgcn_mfma_f32_16x16x16f16(aW1, hA2, bC1, 0, 0, 0);
            floatx4 dB1 = __builtin_amdgcn_mfma_f32_16x16x16f16(aW1, hB1, bC1, 0, 0, 0);
            floatx4 dB2 = __builtin_amdgcn_mfma_f32_16x16x16f16(aW1, hB2, bC1, 0, 0, 0);
#pragma unroll
            for (int e = 0; e < 4; ++e) {
                floatx2 ra = ract2(dA1[e], dA2[e]);
                rA1[e] = ra[0]; rA2[e] = ra[1];
                floatx2 rb = ract2(dB1[e], dB2[e]);
                rB1[e] = rb[0]; rB2[e] = rb[1];
            }
            hA1 = mk4f(rA1); hA2 = mk4f(rA2);
            hB1 = mk4f(rB1); hB2 = mk4f(rB2);
        }
        // ---- Hidden layer 3 + fused final 16->1 (feed r1-r2, A = -2K*Wf) ----
        {
            floatx4 dA1 = __builtin_amdgcn_mfma_f32_16x16x16f16(aW2, hA1, bC2, 0, 0, 0);
            floatx4 dA2 = __builtin_amdgcn_mfma_f32_16x16x16f16(aW2, hA2, bC2, 0, 0, 0);
            floatx4 dB1 = __builtin_amdgcn_mfma_f32_16x16x16f16(aW2, hB1, bC2, 0, 0, 0);
            floatx4 dB2 = __builtin_amdgcn_mfma_f32_16x16x16f16(aW2, hB2, bC2, 0, 0, 0);
#pragma unroll
            for (int e = 0; e < 4; ++e) {
                floatx2 ra = ract2(dA1[e], dA2[e]);
                rA1[e] = ra[0]; rA2[e] = ra[1];
                floatx2 rb = ract2(dB1[e], dB2[e]);
                rB1[e] = rb[0]; rB2[e] = rb[1];
            }
            half4 sA = mk4f(rA1 - rA2);
            half4 sB = mk4f(rB1 - rB2);
            floatx4 drA = __builtin_amdgcn_mfma_f32_16x16x16f16(aWf, sA, zeroC, 0, 0, 0);
            floatx4 drB = __builtin_amdgcn_mfma_f32_16x16x16f16(aWf, sB, zeroC, 0, 0, 0);
            accA += act_pre(drA[0]);
            accB += act_pre(drB[0]);
        }
    }
    if (lane < 16 && valid)
        out[g] = (accA + accB) * 0.041875863808787856f;  // ONE_OVER_DIFF_TOT * DIFF_Q
}

extern "C" void kernel_launch(void* const* d_in, const int* in_sizes, int n_in,
                              void* d_out, int out_size, void* d_ws, size_t ws_size,
                              hipStream_t stream) {
    const float* x  = (const float*)d_in[0];
    const float* Ws = (const float*)d_in[1];
    const float* bs = (const float*)d_in[2];
    const float* Wf = (const float*)d_in[3];
    const float* bf = (const float*)d_in[4];
    const float* ex = (const float*)d_in[5];
    float* out = (float*)d_out;

    const int n_groups = out_size;              // B*N = 262144
    const int waves    = (n_groups + 15) / 16;  // 16 groups per wave
    const int blocks   = (waves + 3) / 4;       // 4 waves per block
    automaton_kernel<<<blocks, 256, 0, stream>>>(x, Ws, bs, Wf, bf, ex, out, n_groups);
}

// Round 12
// 154.087 us; speedup vs baseline: 1.1147x; 1.0343x over previous
//
#include <hip/hip_runtime.h>

typedef __fp16   fp16x2  __attribute__((ext_vector_type(2)));
typedef _Float16 half4   __attribute__((ext_vector_type(4)));
typedef float    floatx2 __attribute__((ext_vector_type(2)));
typedef float    floatx4 __attribute__((ext_vector_type(4)));

// Packed-lane helpers: streams A/B ride in the two components of a floatx2 so
// all full-rate math issues as v_pk_* (dual-pump FP32); trans ops stay scalar.
__device__ __forceinline__ floatx2 exp2p(floatx2 a) {
    floatx2 r = { __builtin_amdgcn_exp2f(a[0]), __builtin_amdgcn_exp2f(a[1]) };
    return r;
}
__device__ __forceinline__ floatx2 rcpp(floatx2 a) {
    floatx2 r = { __builtin_amdgcn_rcpf(a[0]), __builtin_amdgcn_rcpf(a[1]) };
    return r;
}

// Paired r-act (net1/net2) with ONE rcp per stream (Montgomery-2), packed
// across streams: q = 1/(d1 d2); r1 = q d2; r2 = q d1.
// Ranges: hidden |a|<=29, layer-0 |a|<~25 -> product <= 2^58, no overflow.
__device__ __forceinline__ void ract2p(floatx2 a1, floatx2 a2,
                                       floatx2* r1, floatx2* r2) {
    floatx2 d1 = exp2p(a1) + 1.0f;
    floatx2 d2 = exp2p(a2) + 1.0f;
    floatx2 q  = rcpp(d1 * d2);
    *r1 = q * d2;
    *r2 = q * d1;
}
// L3 variant: only the net1-net2 difference is needed:
// r1 - r2 = q*(d2 - d1)  (one fewer rounding than r1,r2 separately).
__device__ __forceinline__ floatx2 ract2d(floatx2 a1, floatx2 a2) {
    floatx2 d1 = exp2p(a1) + 1.0f;
    floatx2 d2 = exp2p(a2) + 1.0f;
    floatx2 q  = rcpp(d1 * d2);
    return q * (d2 - d1);
}

__device__ __forceinline__ half4 mk4f(floatx4 v) {
    fp16x2 lo = __builtin_amdgcn_cvt_pkrtz(v[0], v[1]);
    fp16x2 hi = __builtin_amdgcn_cvt_pkrtz(v[2], v[3]);
    union { fp16x2 h2[2]; half4 h4; } u;
    u.h2[0] = lo; u.h2[1] = hi;
    return u.h4;
}

__global__ __launch_bounds__(256, 4) void automaton_kernel(
    const float* __restrict__ x, const float* __restrict__ Ws,
    const float* __restrict__ bs, const float* __restrict__ Wf,
    const float* __restrict__ bf, const float* __restrict__ extra,
    float* __restrict__ out, int n_groups)
{
    const float K = 2.885390081777927f;  // 2*log2(e)
    const int tid   = blockIdx.x * blockDim.x + threadIdx.x;
    const int wave  = tid >> 6;
    const int lane  = threadIdx.x & 63;
    const int col   = lane & 15;
    const int sub   = lane >> 4;
    const int obase = sub * 4;

    const floatx4 zeroC = {0.f, 0.f, 0.f, 0.f};
    const half4   ones  = {(_Float16)1.f, (_Float16)1.f, (_Float16)1.f, (_Float16)1.f};

    float ex[12];
#pragma unroll
    for (int j = 0; j < 12; ++j) ex[j] = extra[j];

    // ---- Layer 0: live cols (scaled by K), fold extra+bias into c1 ----
    float W0c[4][4], c1[4];
#pragma unroll
    for (int e = 0; e < 4; ++e) {
        const float* row = Ws + (obase + e) * 16;
        floatx4 r0 = *(const floatx4*)(row);
        floatx4 r1 = *(const floatx4*)(row + 4);
        floatx4 r2 = *(const floatx4*)(row + 8);
        floatx4 r3 = *(const floatx4*)(row + 12);
#pragma unroll
        for (int j = 0; j < 4; ++j) W0c[e][j] = r0[j] * K;
        float c = bs[obase + e];
#pragma unroll
        for (int j = 0; j < 4; ++j) c = fmaf(r1[j], ex[j], c);
#pragma unroll
        for (int j = 0; j < 4; ++j) c = fmaf(r2[j], ex[4 + j], c);
#pragma unroll
        for (int j = 0; j < 4; ++j) c = fmaf(r3[j], ex[8 + j], c);
        c1[e] = c * K;
    }

    // ---- Hidden layers 1..3: A'' = f16(-2K*W); c'' = K*b - 0.5*(A''.1) ----
    half4 aW0, aW1, aW2, aWf;
    floatx4 bC0, bC1, bC2;
    {
        floatx4 w1 = *(const floatx4*)(Ws + 256 + col * 16 + obase);
        floatx4 w2 = *(const floatx4*)(Ws + 512 + col * 16 + obase);
        floatx4 w3 = *(const floatx4*)(Ws + 768 + col * 16 + obase);
#pragma unroll
        for (int e = 0; e < 4; ++e) {
            aW0[e] = (_Float16)(w1[e] * (-2.0f * K));
            aW1[e] = (_Float16)(w2[e] * (-2.0f * K));
            aW2[e] = (_Float16)(w3[e] * (-2.0f * K));
        }
        floatx4 s0 = __builtin_amdgcn_mfma_f32_16x16x16f16(aW0, ones, zeroC, 0, 0, 0);
        floatx4 s1 = __builtin_amdgcn_mfma_f32_16x16x16f16(aW1, ones, zeroC, 0, 0, 0);
        floatx4 s2 = __builtin_amdgcn_mfma_f32_16x16x16f16(aW2, ones, zeroC, 0, 0, 0);
        floatx4 b1 = *(const floatx4*)(bs + 16 + obase);
        floatx4 b2 = *(const floatx4*)(bs + 32 + obase);
        floatx4 b3 = *(const floatx4*)(bs + 48 + obase);
#pragma unroll
        for (int e = 0; e < 4; ++e) {
            bC0[e] = fmaf(-0.5f, s0[e], K * b1[e]);
            bC1[e] = fmaf(-0.5f, s1[e], K * b2[e]);
            bC2[e] = fmaf(-0.5f, s2[e], K * b3[e]);
        }
        floatx4 wf = *(const floatx4*)(Wf + obase);
#pragma unroll
        for (int e = 0; e < 4; ++e) aWf[e] = (_Float16)(wf[e] * (-2.0f * K));
    }

    const int g      = wave * 16 + col;
    const bool valid = (g < n_groups);
    const int gl     = valid ? g : (n_groups - 1);
    const float* xp  = x + (size_t)gl * 104;   // 26 channels * 4 floats

    floatx2 accp = {0.f, 0.f};
#pragma unroll 1
    for (int c = 0; c < 13; ++c) {
        // Two independent channel streams packed as floatx2 lanes: A=c, B=c+13.
        floatx4 xvA = *(const floatx4*)(xp + c * 4);
        floatx4 xvB = *(const floatx4*)(xp + (c + 13) * 4);
        floatx2 xq0 = {xvA[0], xvB[0]};
        floatx2 xq1 = {xvA[1], xvB[1]};
        floatx2 xq2 = {xvA[2], xvB[2]};
        floatx2 xq3 = {xvA[3], xvB[3]};

        // ---- Layer 0 (both nets), packed FMA ladder -> paired r-act ----
        floatx4 rA1, rA2, rB1, rB2;
        {
#pragma unroll
            for (int e = 0; e < 4; ++e) {
                floatx2 a1 = {c1[e], c1[e]};
                a1 += W0c[e][0] * xq0;
                a1 += W0c[e][1] * xq1;
                a1 += W0c[e][2] * xq2;
                a1 += W0c[e][3] * xq3;
                floatx2 a2 = {c1[e], c1[e]};
                a2 += W0c[e][0] * xq2;
                a2 += W0c[e][1] * xq3;
                a2 += W0c[e][2] * xq0;
                a2 += W0c[e][3] * xq1;
                floatx2 r1p, r2p;
                ract2p(a1, a2, &r1p, &r2p);
                rA1[e] = r1p[0]; rB1[e] = r1p[1];
                rA2[e] = r2p[0]; rB2[e] = r2p[1];
            }
        }
        half4 hA1 = mk4f(rA1), hA2 = mk4f(rA2);
        half4 hB1 = mk4f(rB1), hB2 = mk4f(rB2);

        // ---- Hidden layer 1 ----
        {
            floatx4 dA1 = __builtin_amdgcn_mfma_f32_16x16x16f16(aW0, hA1, bC0, 0, 0, 0);
            floatx4 dA2 = __builtin_amdgcn_mfma_f32_16x16x16f16(aW0, hA2, bC0, 0, 0, 0);
            floatx4 dB1 = __builtin_amdgcn_mfma_f32_16x16x16f16(aW0, hB1, bC0, 0, 0, 0);
            floatx4 dB2 = __builtin_amdgcn_mfma_f32_16x16x16f16(aW0, hB2, bC0, 0, 0, 0);
#pragma unroll
            for (int e = 0; e < 4; ++e) {
                floatx2 p1 = {dA1[e], dB1[e]};
                floatx2 p2 = {dA2[e], dB2[e]};
                floatx2 r1p, r2p;
                ract2p(p1, p2, &r1p, &r2p);
                rA1[e] = r1p[0]; rB1[e] = r1p[1];
                rA2[e] = r2p[0]; rB2[e] = r2p[1];
            }
            hA1 = mk4f(rA1); hA2 = mk4f(rA2);
            hB1 = mk4f(rB1); hB2 = mk4f(rB2);
        }
        // ---- Hidden layer 2 ----
        {
            floatx4 dA1 = __builtin_amdgcn_mfma_f32_16x16x16f16(aW1, hA1, bC1, 0, 0, 0);
            floatx4 dA2 = __builtin_amdgcn_mfma_f32_16x16x16f16(aW1, hA2, bC1, 0, 0, 0);
            floatx4 dB1 = __builtin_amdgcn_mfma_f32_16x16x16f16(aW1, hB1, bC1, 0, 0, 0);
            floatx4 dB2 = __builtin_amdgcn_mfma_f32_16x16x16f16(aW1, hB2, bC1, 0, 0, 0);
#pragma unroll
            for (int e = 0; e < 4; ++e) {
                floatx2 p1 = {dA1[e], dB1[e]};
                floatx2 p2 = {dA2[e], dB2[e]};
                floatx2 r1p, r2p;
                ract2p(p1, p2, &r1p, &r2p);
                rA1[e] = r1p[0]; rB1[e] = r1p[1];
                rA2[e] = r2p[0]; rB2[e] = r2p[1];
            }
            hA1 = mk4f(rA1); hA2 = mk4f(rA2);
            hB1 = mk4f(rB1); hB2 = mk4f(rB2);
        }
        // ---- Hidden layer 3 + fused final 16->1 (only r1-r2 needed) ----
        {
            floatx4 dA1 = __builtin_amdgcn_mfma_f32_16x16x16f16(aW2, hA1, bC2, 0, 0, 0);
            floatx4 dA2 = __builtin_amdgcn_mfma_f32_16x16x16f16(aW2, hA2, bC2, 0, 0, 0);
            floatx4 dB1 = __builtin_amdgcn_mfma_f32_16x16x16f16(aW2, hB1, bC2, 0, 0, 0);
            floatx4 dB2 = __builtin_amdgcn_mfma_f32_16x16x16f16(aW2, hB2, bC2, 0, 0, 0);
            floatx4 sAv, sBv;
#pragma unroll
            for (int e = 0; e < 4; ++e) {
                floatx2 p1 = {dA1[e], dB1[e]};
                floatx2 p2 = {dA2[e], dB2[e]};
                floatx2 sp = ract2d(p1, p2);
                sAv[e] = sp[0]; sBv[e] = sp[1];
            }
            half4 sA = mk4f(sAv);
            half4 sB = mk4f(sBv);
            floatx4 drA = __builtin_amdgcn_mfma_f32_16x16x16f16(aWf, sA, zeroC, 0, 0, 0);
            floatx4 drB = __builtin_amdgcn_mfma_f32_16x16x16f16(aWf, sB, zeroC, 0, 0, 0);
            // Final act, packed epilogue (trans scalar)
            floatx2 drp = {drA[0], drB[0]};
            floatx2 dd  = exp2p(drp) + 1.0f;
            floatx2 rr  = rcpp(dd);
            accp += 1.0f + rr * -2.0f;
        }
    }
    if (lane < 16 && valid)
        out[g] = (accp[0] + accp[1]) * 0.041875863808787856f;  // ONE_OVER_DIFF_TOT * DIFF_Q
}

extern "C" void kernel_launch(void* const* d_in, const int* in_sizes, int n_in,
                              void* d_out, int out_size, void* d_ws, size_t ws_size,
                              hipStream_t stream) {
    const float* x  = (const float*)d_in[0];
    const float* Ws = (const float*)d_in[1];
    const float* bs = (const float*)d_in[2];
    const float* Wf = (const float*)d_in[3];
    const float* bf = (const float*)d_in[4];
    const float* ex = (const float*)d_in[5];
    float* out = (float*)d_out;

    const int n_groups = out_size;              // B*N = 262144
    const int waves    = (n_groups + 15) / 16;  // 16 groups per wave
    const int blocks   = (waves + 3) / 4;       // 4 waves per block
    automaton_kernel<<<blocks, 256, 0, stream>>>(x, Ws, bs, Wf, bf, ex, out, n_groups);
}